// Round 6
// baseline (118.373 us; speedup 1.0000x reference)
//
#include <hip/hip_runtime.h>
#include <hip/hip_bf16.h>
#include <stdint.h>

// B=32, C=256, H=W=32, 3x3 conv pad 1 -> implicit GEMM in INT8.
// M = 32768 (b,h,w), N = 256 (co), K = 2304; k = (kh*3+kw)*256 + ci.
// A staged ONCE per block (52KB halo in LDS, 1 barrier total); B read
// per-fragment from L2 in precomputed MFMA layout. Register-tightened:
// single-buffer A frags, ping-pong B only (fits 128-VGPR cap, no spills).

typedef int i32x4 __attribute__((ext_vector_type(4)));
typedef float f32x4 __attribute__((ext_vector_type(4)));

__device__ __forceinline__ void gload_lds16(const void* g, const void* lds) {
    __builtin_amdgcn_global_load_lds(
        (const __attribute__((address_space(1))) unsigned int*)(uintptr_t)g,
        (__attribute__((address_space(3))) unsigned int*)(uintptr_t)lds,
        16, 0, 0);
}

// weight (float [co][ci][3][3]) -> ternary int8 in MFMA-fragment order:
// B'[(co>>4)][kt 0..35][kq 0..3][co&15][j 0..15], elem = Wq[co][k=kt*64+kq*16+j].
__global__ __launch_bounds__(256) void quant_w_kernel(const float* __restrict__ w,
                                                      signed char* __restrict__ wq) {
    __shared__ signed char tile[2304];    // k-ordered: [khkw*256 + ci]
    const int co = blockIdx.x;
    const int t = threadIdx.x;
#pragma unroll
    for (int p = 0; p < 9; ++p) {
        const int idx = p * 256 + t;                 // = ci*9 + khkw
        const float v = w[co * 2304 + idx];
        const int ci = idx / 9;
        const int khkw = idx - 9 * ci;
        const float q = fminf(fmaxf(rintf(v), -1.f), 1.f);
        tile[khkw * 256 + ci] = (signed char)(int)q;
    }
    __syncthreads();
    if (t < 144) {                                   // t = kt*4 + kq
        const int kt = t >> 2, kq = t & 3;
        const uint4 v = *(const uint4*)(tile + t * 16);
        *(uint4*)(wq + ((size_t)((co >> 4) * 36 + kt) << 10) + kq * 256 + (co & 15) * 16) = v;
    }
}

// x (float NCHW) -> int8, padded NHWC [b][34][34][ci], borders zeroed.
__global__ __launch_bounds__(256) void quant_x_kernel(const float* __restrict__ x,
                                                      signed char* __restrict__ xpad) {
    __shared__ signed char tile[32 * 272];
    const int t = threadIdx.x;
    const int b = blockIdx.x / 34;
    const int hp = blockIdx.x % 34;
    signed char* rowbase = xpad + (size_t)((b * 34 + hp) * 34) * 256;
    const uint4 z = {0u, 0u, 0u, 0u};
    if (hp == 0 || hp == 33) {
        for (int i = t; i < 544; i += 256) *(uint4*)(rowbase + i * 16) = z;
        return;
    }
    const int h = hp - 1;
    const int w = t & 31;
    const int cg = (t >> 5) * 4;
#pragma unroll
    for (int p = 0; p < 8; ++p) {
        const int ci = p * 32 + cg;
        unsigned packed = 0;
#pragma unroll
        for (int k = 0; k < 4; ++k) {
            const float v = x[(((size_t)(b * 256 + ci + k)) * 32 + h) * 32 + w];
            float q = fminf(fmaxf(rintf(__fmul_rn(v, 128.f)), -128.f), 127.f);
            packed |= ((unsigned)(unsigned char)(signed char)(int)q) << (8 * k);
        }
        *(unsigned*)(tile + w * 272 + ci) = packed;
    }
    __syncthreads();
#pragma unroll
    for (int q = 0; q < 2; ++q) {
        const int wp = q * 16 + (t >> 4);
        const int ci16 = (t & 15) * 16;
        uint4 v = *(const uint4*)(tile + wp * 272 + ci16);
        *(uint4*)(rowbase + (size_t)(wp + 1) * 256 + ci16) = v;
    }
    if (t < 32) {
        const int wp = (t >> 4) * 33;
        *(uint4*)(rowbase + (size_t)wp * 256 + (t & 15) * 16) = z;
    }
}

// GEMM: grid 512 (256 m-tiles x 2 n-tiles), 512 threads = 8 waves (2m x 4n).
// Wave = 64m x 32n: 4 m-frags x 2 n-frags of 16x16x64 i8.
// LDS: A halo only, 6 rows x 34 wp x 256 ci = 52,224 B, xor-swizzled chunks.
__global__ __launch_bounds__(512, 4) void conv_gemm_kernel(
    const signed char* __restrict__ xpad, const signed char* __restrict__ wqm,
    const float* __restrict__ gamma, const float* __restrict__ beta,
    const float* __restrict__ mean, const float* __restrict__ var,
    float* __restrict__ out)
{
    __shared__ signed char As[6 * 34 * 256];   // [r=hh*34+wp][chunk ^ (r&15)][16]

    const int tid = threadIdx.x;
    const int wv = tid >> 6;
    const int lane = tid & 63;
    const int l16 = lane & 15;
    const int l4 = lane >> 4;

    const int mt = blockIdx.x >> 1;
    const int n0 = (blockIdx.x & 1) * 128;
    const int b = mt >> 3;
    const int h0 = (mt & 7) * 4;
    const int wave_m = wv & 1;    // 2 waves over m (64 each)
    const int wave_n = wv >> 1;   // 4 waves over n (32 each)

    // ---- stage A halo once: padded rows h0..h0+5, all 34 wp, all 256 ci ----
    const signed char* xbase = xpad + (size_t)(b * 34 + h0) * 34 * 256;
#pragma unroll
    for (int p = 0; p < 7; ++p) {                // 51 wave-shots x 1KB = 52,224B
        const int i = p * 8 + wv;
        if (i < 51) {
            const int d = i * 64 + lane;
            const int r = d >> 4;
            const int c = d & 15;
            gload_lds16(xbase + r * 256 + ((c ^ (r & 15)) << 4), As + i * 1024);
        }
    }
    __syncthreads();   // the ONLY barrier

    // per-frag A row bases: frag i -> h = h0+wave_m*2+(i>>1), w = (i&1)*16 + l16
    int r0[4];
#pragma unroll
    for (int i = 0; i < 4; ++i)
        r0[i] = (wave_m * 2 + (i >> 1)) * 34 + (i & 1) * 16 + l16;

    // B frag pointers (L2-hot, MFMA layout): frag j -> co_blk = n0/16 + wave_n*2 + j
    const signed char* bp0 = wqm + (((size_t)((n0 >> 4) + wave_n * 2 + 0) * 36) << 10) + lane * 16;
    const signed char* bp1 = wqm + (((size_t)((n0 >> 4) + wave_n * 2 + 1) * 36) << 10) + lane * 16;

    i32x4 acc[4][2];
#pragma unroll
    for (int i = 0; i < 4; i++)
#pragma unroll
        for (int j = 0; j < 2; j++) acc[i][j] = (i32x4){0, 0, 0, 0};

    i32x4 aC[4], b0[2], b1[2];   // 16 + 8 + 8 data VGPRs live (+32 acc)

#define LOAD_B(kt, dst) { dst[0] = *(const i32x4*)(bp0 + (kt) * 1024); \
                          dst[1] = *(const i32x4*)(bp1 + (kt) * 1024); }
#define LOAD_A(kt) { const int khkw = (kt) >> 2; \
                     const int roff = khkw + 31 * ((khkw * 11) >> 5); /* kh*34+kw */ \
                     const int cb = ((kt) & 3) * 4 + l4; \
                     _Pragma("unroll") \
                     for (int i = 0; i < 4; ++i) { \
                         const int r = r0[i] + roff; \
                         aC[i] = *(const i32x4*)(As + r * 256 + ((cb ^ (r & 15)) << 4)); \
                     } }
#define MFMA(bf) { _Pragma("unroll") \
                   for (int i = 0; i < 4; ++i) \
                       _Pragma("unroll") \
                       for (int j = 0; j < 2; ++j) \
                           acc[i][j] = __builtin_amdgcn_mfma_i32_16x16x64_i8(aC[i], bf[j], acc[i][j], 0, 0, 0); }

    LOAD_B(0, b0)
    for (int kt = 0; kt < 36; kt += 2) {   // rolled; A single-buffered, B ping-pong
        LOAD_A(kt)
        LOAD_B(kt + 1, b1)
        MFMA(b0)
        LOAD_A(kt + 1)
        if (kt + 2 < 36) LOAD_B(kt + 2, b0)
        MFMA(b1)
    }

    // ---- epilogue: C/D col = l16 (n), row = l4*4 + r (m within frag) ----
#pragma unroll
    for (int j = 0; j < 2; ++j) {
        const int co = n0 + wave_n * 32 + j * 16 + l16;
        const float iv = __fdiv_rn(gamma[co], __fsqrt_rn(__fadd_rn(var[co], 1e-4f)));
        const float bias = __fsub_rn(beta[co], __fmul_rn(mean[co], iv));
#pragma unroll
        for (int i = 0; i < 4; ++i) {
            const int h = h0 + wave_m * 2 + (i >> 1);
            const int w = (i & 1) * 16 + l4 * 4;
            f32x4 v;
#pragma unroll
            for (int r = 0; r < 4; r++) {
                const float y = __fmul_rn((float)acc[i][j][r], 0.0078125f);  // exact pow2
                const float t = __fadd_rn(__fmul_rn(y, iv), bias);           // no FMA: match np
                float z = rintf(__fmul_rn(t, 2.f));
                z = fminf(fmaxf(z, -2.f), 1.f);
                v[r] = __fmul_rn(z, 0.5f);
            }
            *(f32x4*)(&out[(((size_t)(b * 256 + co)) * 32 + h) * 32 + w]) = v;
        }
    }
#undef LOAD_B
#undef LOAD_A
#undef MFMA
}

extern "C" void kernel_launch(void* const* d_in, const int* in_sizes, int n_in,
                              void* d_out, int out_size, void* d_ws, size_t ws_size,
                              hipStream_t stream) {
    const float* x      = (const float*)d_in[0];
    const float* weight = (const float*)d_in[1];
    const float* gamma  = (const float*)d_in[2];
    const float* beta   = (const float*)d_in[3];
    const float* rmean  = (const float*)d_in[4];
    const float* rvar   = (const float*)d_in[5];
    float* out = (float*)d_out;

    signed char* wq   = (signed char*)d_ws;                 // 589,824 B (MFMA layout)
    signed char* xpad = (signed char*)d_ws + (1 << 20);     // 9,469,952 B

    quant_w_kernel<<<256, 256, 0, stream>>>(weight, wq);
    quant_x_kernel<<<1088, 256, 0, stream>>>(x, xpad);
    conv_gemm_kernel<<<512, 512, 0, stream>>>(xpad, wq, gamma, beta, rmean, rvar, out);
}

// Round 8
// 117.766 us; speedup vs baseline: 1.0052x; 1.0052x over previous
//
#include <hip/hip_runtime.h>
#include <hip/hip_bf16.h>
#include <stdint.h>

// B=32, C=256, H=W=32, 3x3 conv pad 1 -> implicit GEMM in INT8.
// M = 32768 (b,h,w), N = 256 (co), K = 2304; k = (kh*3+kw)*256 + ci.
// Two dispatches: (1) merged quant kernel (x -> int8 padded NHWC; w -> ternary
// int8 in MFMA fragment order), (2) GEMM with A staged once per block (52KB
// halo in LDS, 1 barrier) and B streamed per-fragment from L2.

typedef int i32x4 __attribute__((ext_vector_type(4)));
typedef float f32x4 __attribute__((ext_vector_type(4)));

__device__ __forceinline__ void gload_lds16(const void* g, const void* lds) {
    __builtin_amdgcn_global_load_lds(
        (const __attribute__((address_space(1))) unsigned int*)(uintptr_t)g,
        (__attribute__((address_space(3))) unsigned int*)(uintptr_t)lds,
        16, 0, 0);
}

// Merged quantization. Blocks 0..1087: x-row (b = blk/34, hp = blk%34) ->
// int8 padded NHWC [b][34][34][ci], borders zeroed. Blocks 1088..1343:
// weight channel co = blk-1088 -> ternary int8, MFMA-fragment order
// B'[(co>>4)][kt][kq][co&15][j], elem = Wq[co][k=kt*64+kq*16+j].
__global__ __launch_bounds__(256) void quant_kernel(
    const float* __restrict__ x, const float* __restrict__ w,
    signed char* __restrict__ xpad, signed char* __restrict__ wq)
{
    __shared__ signed char tile[32 * 272];
    const int t = threadIdx.x;
    const int blk = blockIdx.x;

    if (blk >= 1088) {                        // ---- weight path ----
        const int co = blk - 1088;
        signed char* wt = tile;               // reuse as [khkw*256 + ci]
#pragma unroll
        for (int p = 0; p < 9; ++p) {
            const int idx = p * 256 + t;      // = ci*9 + khkw
            const float v = w[co * 2304 + idx];
            const int ci = idx / 9;
            const int khkw = idx - 9 * ci;
            const float q = fminf(fmaxf(rintf(v), -1.f), 1.f);
            wt[khkw * 256 + ci] = (signed char)(int)q;
        }
        __syncthreads();
        if (t < 144) {                        // t = kt*4 + kq
            const int kt = t >> 2, kq = t & 3;
            const uint4 v = *(const uint4*)(wt + t * 16);
            *(uint4*)(wq + ((size_t)((co >> 4) * 36 + kt) << 10) + kq * 256 + (co & 15) * 16) = v;
        }
        return;
    }

    // ---- x path ----
    const int b = blk / 34;
    const int hp = blk % 34;
    signed char* rowbase = xpad + (size_t)((b * 34 + hp) * 34) * 256;
    const uint4 z = {0u, 0u, 0u, 0u};
    if (hp == 0 || hp == 33) {                // whole padded row = zeros
        for (int i = t; i < 544; i += 256) *(uint4*)(rowbase + i * 16) = z;
        return;
    }
    const int h = hp - 1;
    const int ww = t & 31;
    const int cg = (t >> 5) * 4;
#pragma unroll
    for (int p = 0; p < 8; ++p) {
        const int ci = p * 32 + cg;
        unsigned packed = 0;
#pragma unroll
        for (int k = 0; k < 4; ++k) {
            const float v = x[(((size_t)(b * 256 + ci + k)) * 32 + h) * 32 + ww];
            float q = fminf(fmaxf(rintf(__fmul_rn(v, 128.f)), -128.f), 127.f);
            packed |= ((unsigned)(unsigned char)(signed char)(int)q) << (8 * k);
        }
        *(unsigned*)(tile + ww * 272 + ci) = packed;
    }
    __syncthreads();
#pragma unroll
    for (int q = 0; q < 2; ++q) {             // interior: 16B/lane, coalesced
        const int wp = q * 16 + (t >> 4);
        const int ci16 = (t & 15) * 16;
        uint4 v = *(const uint4*)(tile + wp * 272 + ci16);
        *(uint4*)(rowbase + (size_t)(wp + 1) * 256 + ci16) = v;
    }
    if (t < 32) {                             // zero border cols wp=0,33
        const int wp = (t >> 4) * 33;
        *(uint4*)(rowbase + (size_t)wp * 256 + (t & 15) * 16) = z;
    }
}

// GEMM: grid 512 (256 m-tiles x 2 n-tiles), 512 threads = 8 waves (2m x 4n).
// Wave = 64m x 32n: 4 m-frags x 2 n-frags of 16x16x64 i8.
// LDS: A halo only, 6 rows x 34 wp x 256 ci = 52,224 B, xor-swizzled chunks.
__global__ __launch_bounds__(512, 4) void conv_gemm_kernel(
    const signed char* __restrict__ xpad, const signed char* __restrict__ wqm,
    const float* __restrict__ gamma, const float* __restrict__ beta,
    const float* __restrict__ mean, const float* __restrict__ var,
    float* __restrict__ out)
{
    __shared__ signed char As[6 * 34 * 256];   // [r=hh*34+wp][chunk ^ (r&15)][16]

    const int tid = threadIdx.x;
    const int wv = tid >> 6;
    const int lane = tid & 63;
    const int l16 = lane & 15;
    const int l4 = lane >> 4;

    const int mt = blockIdx.x >> 1;
    const int n0 = (blockIdx.x & 1) * 128;
    const int b = mt >> 3;
    const int h0 = (mt & 7) * 4;
    const int wave_m = wv & 1;    // 2 waves over m (64 each)
    const int wave_n = wv >> 1;   // 4 waves over n (32 each)

    // ---- stage A halo once: padded rows h0..h0+5, all 34 wp, all 256 ci ----
    const signed char* xbase = xpad + (size_t)(b * 34 + h0) * 34 * 256;
#pragma unroll
    for (int p = 0; p < 7; ++p) {                // 51 wave-shots x 1KB = 52,224B
        const int i = p * 8 + wv;
        if (i < 51) {
            const int d = i * 64 + lane;
            const int r = d >> 4;
            const int c = d & 15;
            gload_lds16(xbase + r * 256 + ((c ^ (r & 15)) << 4), As + i * 1024);
        }
    }
    __syncthreads();   // the ONLY barrier

    int r0[4];
#pragma unroll
    for (int i = 0; i < 4; ++i)
        r0[i] = (wave_m * 2 + (i >> 1)) * 34 + (i & 1) * 16 + l16;

    const signed char* bp0 = wqm + (((size_t)((n0 >> 4) + wave_n * 2 + 0) * 36) << 10) + lane * 16;
    const signed char* bp1 = wqm + (((size_t)((n0 >> 4) + wave_n * 2 + 1) * 36) << 10) + lane * 16;

    i32x4 acc[4][2];
#pragma unroll
    for (int i = 0; i < 4; i++)
#pragma unroll
        for (int j = 0; j < 2; j++) acc[i][j] = (i32x4){0, 0, 0, 0};

    i32x4 aP[2][4], bP[2][2];

#define LOAD_B(kt, dst) { dst[0] = *(const i32x4*)(bp0 + (kt) * 1024); \
                          dst[1] = *(const i32x4*)(bp1 + (kt) * 1024); }
#define LOAD_A(kt, dst) { const int khkw = (kt) >> 2; \
                          const int kh = khkw / 3; \
                          const int kw = khkw - 3 * kh; \
                          const int roff = kh * 34 + kw; \
                          const int cb = ((kt) & 3) * 4 + l4; \
                          _Pragma("unroll") \
                          for (int i = 0; i < 4; ++i) { \
                              const int r = r0[i] + roff; \
                              dst[i] = *(const i32x4*)(As + r * 256 + ((cb ^ (r & 15)) << 4)); \
                          } }
#define MFMA(af, bf) { _Pragma("unroll") \
                       for (int i = 0; i < 4; ++i) \
                           _Pragma("unroll") \
                           for (int j = 0; j < 2; ++j) \
                               acc[i][j] = __builtin_amdgcn_mfma_i32_16x16x64_i8(af[i], bf[j], acc[i][j], 0, 0, 0); }

    LOAD_B(0, bP[0])
    LOAD_A(0, aP[0])
#pragma unroll
    for (int kt = 0; kt < 36; ++kt) {            // full unroll: offsets fold
        const int cur = kt & 1, nxt = cur ^ 1;
        if (kt + 1 < 36) { LOAD_B(kt + 1, bP[nxt]) LOAD_A(kt + 1, aP[nxt]) }
        MFMA(aP[cur], bP[cur])
    }

    // ---- epilogue: C/D col = l16 (n), row = l4*4 + r (m within frag) ----
#pragma unroll
    for (int j = 0; j < 2; ++j) {
        const int co = n0 + wave_n * 32 + j * 16 + l16;
        const float iv = __fdiv_rn(gamma[co], __fsqrt_rn(__fadd_rn(var[co], 1e-4f)));
        const float bias = __fsub_rn(beta[co], __fmul_rn(mean[co], iv));
#pragma unroll
        for (int i = 0; i < 4; ++i) {
            const int h = h0 + wave_m * 2 + (i >> 1);
            const int w = (i & 1) * 16 + l4 * 4;
            f32x4 v;
#pragma unroll
            for (int r = 0; r < 4; r++) {
                const float y = __fmul_rn((float)acc[i][j][r], 0.0078125f);  // exact pow2
                const float t = __fadd_rn(__fmul_rn(y, iv), bias);           // no FMA: match np
                float z = rintf(__fmul_rn(t, 2.f));
                z = fminf(fmaxf(z, -2.f), 1.f);
                v[r] = __fmul_rn(z, 0.5f);
            }
            *(f32x4*)(&out[(((size_t)(b * 256 + co)) * 32 + h) * 32 + w]) = v;
        }
    }
#undef LOAD_B
#undef LOAD_A
#undef MFMA
}

extern "C" void kernel_launch(void* const* d_in, const int* in_sizes, int n_in,
                              void* d_out, int out_size, void* d_ws, size_t ws_size,
                              hipStream_t stream) {
    const float* x      = (const float*)d_in[0];
    const float* weight = (const float*)d_in[1];
    const float* gamma  = (const float*)d_in[2];
    const float* beta   = (const float*)d_in[3];
    const float* rmean  = (const float*)d_in[4];
    const float* rvar   = (const float*)d_in[5];
    float* out = (float*)d_out;

    signed char* wq   = (signed char*)d_ws;                 // 589,824 B (MFMA layout)
    signed char* xpad = (signed char*)d_ws + (1 << 20);     // 9,469,952 B

    quant_kernel<<<1344, 256, 0, stream>>>(x, weight, xpad, wq);
    conv_gemm_kernel<<<512, 512, 0, stream>>>(xpad, wq, gamma, beta, rmean, rvar, out);
}